// Round 17
// baseline (767.890 us; speedup 1.0000x reference)
//
#include <hip/hip_runtime.h>

#define DEVINL __device__ __forceinline__

typedef __bf16 bf16x8 __attribute__((ext_vector_type(8)));
typedef float  f32x4  __attribute__((ext_vector_type(4)));

constexpr int KK = 4096;        // K
constexpr int NN = 11008;       // N
constexpr int NG = 32;          // K / group_size(128)

DEVINL unsigned short f2bf(float f){
  union { float f; unsigned u; } v; v.f = f;
  unsigned r = v.u + 0x7FFF + ((v.u >> 16) & 1);   // RNE; inputs finite here
  return (unsigned short)(r >> 16);
}
DEVINL unsigned pack2(float lo, float hi){
  return (unsigned)f2bf(lo) | ((unsigned)f2bf(hi) << 16);
}
DEVINL void gload16(const void* g, void* l){
  __builtin_amdgcn_global_load_lds(
      (const __attribute__((address_space(1))) void*)g,
      (__attribute__((address_space(3))) void*)l, 16, 0, 0);
}

// ------- merged pre-kernel: dequant W -> bf16 [N][K]  ||  cvt x -> bf16 ----
// Runs both conversions in one grid so they overlap (were serial, ~50us).
constexpr int DQ_BLOCKS = (NN * (KK / 8)) / 256;       // 22016
__global__ __launch_bounds__(256) void k_prep(const int* __restrict__ W,
                                              const float* __restrict__ S,
                                              const float* __restrict__ X,
                                              unsigned short* __restrict__ WB,
                                              unsigned short* __restrict__ XB){
  if ((int)blockIdx.x < DQ_BLOCKS){
    int t = blockIdx.x * 256 + threadIdx.x;   // quad id; total NN*(KK/8)
    int row = t >> 9;                         // 512 quads per N-row
    int kp0 = (t & 511) << 2;
    int g   = kp0 >> 6;
    float s = S[row * NG + g];
    const int4 p = reinterpret_cast<const int4*>(W)[t];
    const int* pb = reinterpret_cast<const int*>(&p);
    unsigned q[4];
    #pragma unroll
    for (int i = 0; i < 4; ++i){
      int b = pb[i];
      float lo = ((float)(b & 15)        - 8.0f) * s;
      float hi = ((float)((b >> 4) & 15) - 8.0f) * s;
      q[i] = pack2(lo, hi);
    }
    reinterpret_cast<int4*>(WB)[t] = make_int4((int)q[0], (int)q[1], (int)q[2], (int)q[3]);
  } else {
    int t = (blockIdx.x - DQ_BLOCKS) * 256 + threadIdx.x;   // octet id
    const float4* src = reinterpret_cast<const float4*>(X) + (size_t)t * 2;
    float4 a = src[0], b = src[1];
    reinterpret_cast<int4*>(XB)[t] = make_int4(
        (int)pack2(a.x, a.y), (int)pack2(a.z, a.w),
        (int)pack2(b.x, b.y), (int)pack2(b.z, b.w));
  }
}

// ======= R17 = R16 (best verified) + banded raster for L2/L3 locality =====
// 256x256 tile, 1024 thr = 16 waves (4m x 4n) x 64x64/wave, BK=64, dbuf,
// 1 barrier + 1 own-wave vmcnt drain per K-tile (R9/R16-verified schedule).
// NEW: block raster in bands of 8 mt — within a band the 8 A-panels (16MB)
// stay cache-hot and each B-panel is read once per band, cutting ideal HBM
// fetch from ~1.5GB to ~0.43GB. Pure index bijection; applied after the
// XCD swizzle. Session map (R6-R15): pipelined-read schedules spill
// (~260 regs/wave > 256 HW); 16-wave blocks cap at 128 regs/wave; smaller
// tiles go HBM-bound; more barriers/tiles lose to lockstep.
constexpr int BM2 = 256, BN2 = 256, BK2 = 64;
constexpr int HBY = 16384;      // half-tile bytes (128 rows x 64 K x bf16)
constexpr int BUFBY = 65536;    // one dbuf buffer (A0,A1,B0,B1)
constexpr int MT = 32, NT_TILES = 43;         // grid = 32 x 43 = 1376
constexpr int BAND = 8;                        // mt band height

#define WAIT0  asm volatile("s_waitcnt vmcnt(0)" ::: "memory")
#define BAR()  do { __builtin_amdgcn_s_barrier(); asm volatile("" ::: "memory"); } while (0)

__global__ __launch_bounds__(1024, 1) void k_gemm16(const unsigned short* __restrict__ A,
                                                    const unsigned short* __restrict__ B,
                                                    const float* __restrict__ Bias,
                                                    float* __restrict__ C){
  __shared__ char smem[131072];
  const int tid = threadIdx.x, lane = tid & 63, wid = tid >> 6;   // wid 0..15
  const int wm = wid >> 2, wn = wid & 3;       // 4 x 4 waves
  const int lr = lane & 15, hi = lane >> 4;
  // XCD-aware swizzle (grid 1376 % 8 == 0), then banded raster: within each
  // band of BAND mt-rows, consecutive wg iterate mt fastest (A-panels hot),
  // nt advances every BAND blocks (B-panel shared by BAND consecutive wg).
  const int cpx = gridDim.x >> 3;
  const int wg  = (blockIdx.x & 7) * cpx + (blockIdx.x >> 3);
  const int band    = wg / (BAND * NT_TILES);           // 0..3
  const int in_band = wg % (BAND * NT_TILES);
  const int nt = in_band / BAND;
  const int mt = band * BAND + (in_band % BAND);
  const char* Ab = (const char*)(A + (size_t)mt * BM2 * KK);
  const char* Bb = (const char*)(B + (size_t)nt * BN2 * KK);
  const int srow  = tid >> 3;                  // staging row (0..127)
  const int scolb = (tid & 7) * 16;            // staging col byte (0..112)

  // Stage one half-tile (sel: 0=A0,1=A1,2=B0,3=B1): 1 gload16 per thread.
  auto stage_half = [&](int buf, int sel, int kt){
    const char* base = ((sel >= 2) ? Bb : Ab) + (size_t)((sel & 1) * 128) * KK * 2;
    const char* src = base + (size_t)srow * (KK * 2) + kt * (BK2 * 2)
                    + (scolb ^ ((srow & 7) << 4));           // inverse-swizzled src
    char* dst = smem + buf * BUFBY + sel * HBY + tid * 16;   // linear dst
    gload16(src, dst);
  };
  // Swizzled LDS fragment read (16B).
  auto frag = [&](int buf, int sel, int row, int bcol) -> bf16x8 {
    return *reinterpret_cast<const bf16x8*>(
        smem + buf * BUFBY + sel * HBY + row * 128 + (bcol ^ ((row & 7) << 4)));
  };

  const int selA = wm >> 1;                    // this wave's A-half
  const int rA0  = (wm & 1) * 64;              // row base within half
  const int selB = 2 + (wn >> 1);              // this wave's B-half
  const int cB0  = (wn & 1) * 64;              // col base within half

  f32x4 acc[4][4] = {};

  // Prologue: stage all 4 halves of K-tile 0, drain, barrier.
  stage_half(0, 0, 0); stage_half(0, 1, 0);
  stage_half(0, 2, 0); stage_half(0, 3, 0);
  WAIT0;
  BAR();

  const int NT = KK / BK2;                     // 64 K-tiles
  for (int t = 0; t < NT; ++t){
    const int buf = t & 1;
    const bool pf = (t + 1 < NT);
    if (pf){                                   // issue next-tile stages first:
      stage_half(buf ^ 1, 0, t + 1);           // in flight across the whole
      stage_half(buf ^ 1, 1, t + 1);           // tile body -> HBM/L2 latency
      stage_half(buf ^ 1, 2, t + 1);           // covered before the WAIT0.
      stage_half(buf ^ 1, 3, t + 1);
    }
    #pragma unroll
    for (int ks = 0; ks < 2; ++ks){            // ks-split keeps frags at 32 VGPR
      bf16x8 af[4], bf[4];
      #pragma unroll
      for (int i = 0; i < 4; ++i)
        af[i] = frag(buf, selA, rA0 + i*16 + lr, ks*64 + hi*16);
      #pragma unroll
      for (int j = 0; j < 4; ++j)
        bf[j] = frag(buf, selB, cB0 + j*16 + lr, ks*64 + hi*16);
      #pragma unroll
      for (int i = 0; i < 4; ++i)
        #pragma unroll
        for (int j = 0; j < 4; ++j)
          acc[i][j] = __builtin_amdgcn_mfma_f32_16x16x32_bf16(af[i], bf[j], acc[i][j], 0, 0, 0);
    }
    if (pf) WAIT0;                             // own 4 stages landed (issued ~1 tile ago)
    BAR();                                     // all waves: staged data global, reads done
  }

  // Epilogue: bias + fp32 store.
  const int cmb = mt * BM2, cnb = nt * BN2;
  #pragma unroll
  for (int j = 0; j < 4; ++j){
    int col = cnb + wn * 64 + j * 16 + lr;
    float bv = Bias[col];
    #pragma unroll
    for (int i = 0; i < 4; ++i){
      int row0 = cmb + wm * 64 + i * 16 + hi * 4;
      #pragma unroll
      for (int r = 0; r < 4; ++r)
        C[(size_t)(row0 + r) * NN + col] = acc[i][j][r] + bv;
    }
  }
}

// ---------------- fallback (verified round 3): A fp32, reg-staged ---------
constexpr int BM = 128, BN = 128, BK = 32;
__global__ __launch_bounds__(256) void k_dequant(const int* __restrict__ W,
                                                 const float* __restrict__ S,
                                                 unsigned short* __restrict__ WB){
  int t = blockIdx.x * 256 + threadIdx.x;
  int row = t >> 9;
  int kp0 = (t & 511) << 2;
  int g   = kp0 >> 6;
  float s = S[row * NG + g];
  const int4 p = reinterpret_cast<const int4*>(W)[t];
  const int* pb = reinterpret_cast<const int*>(&p);
  unsigned q[4];
  #pragma unroll
  for (int i = 0; i < 4; ++i){
    int b = pb[i];
    float lo = ((float)(b & 15)        - 8.0f) * s;
    float hi = ((float)((b >> 4) & 15) - 8.0f) * s;
    q[i] = pack2(lo, hi);
  }
  reinterpret_cast<int4*>(WB)[t] = make_int4((int)q[0], (int)q[1], (int)q[2], (int)q[3]);
}

__global__ __launch_bounds__(256) void k_gemm_ws(const float* __restrict__ A,
                                                 const unsigned short* __restrict__ B,
                                                 const float* __restrict__ Bias,
                                                 float* __restrict__ C){
  __shared__ unsigned short As[2][BM][BK];
  __shared__ unsigned short Bs[2][BN][BK];
  const int tid = threadIdx.x;
  const int NT = NN / BN;
  const int mt = blockIdx.x / NT, nt = blockIdx.x % NT;
  const float*          Ab = A + (size_t)mt * BM * KK;
  const unsigned short* Bb = B + (size_t)nt * BN * KK;
  const int lane = tid & 63, wid = tid >> 6;
  const int wm = wid >> 1, wn = wid & 1;
  const int lr = lane & 15, lk = (lane >> 4) << 3;

  auto ld = [&](int kt, float4* ra, int4* rb){
    #pragma unroll
    for (int r = 0; r < 2; ++r){
      int c = r * 256 + tid, row = c >> 2, k0 = (c & 3) << 3;
      const float* src = Ab + (size_t)row * KK + kt * BK + k0;
      ra[2*r]   = *reinterpret_cast<const float4*>(src);
      ra[2*r+1] = *reinterpret_cast<const float4*>(src + 4);
      rb[r] = *reinterpret_cast<const int4*>(Bb + (size_t)row * KK + kt * BK + k0);
    }
  };
  auto st = [&](int buf, const float4* ra, const int4* rb){
    #pragma unroll
    for (int r = 0; r < 2; ++r){
      int c = r * 256 + tid, row = c >> 2, k0 = (c & 3) << 3;
      unsigned q[4];
      #pragma unroll
      for (int i = 0; i < 4; ++i)
        q[i] = pack2(ra[2*r + (i >> 1)][(i & 1) * 2], ra[2*r + (i >> 1)][(i & 1) * 2 + 1]);
      *reinterpret_cast<int4*>(&As[buf][row][k0]) =
          make_int4((int)q[0], (int)q[1], (int)q[2], (int)q[3]);
      *reinterpret_cast<int4*>(&Bs[buf][row][k0]) = rb[r];
    }
  };

  f32x4 acc[4][4] = {};
  {
    float4 ra[4]; int4 rb[2];
    ld(0, ra, rb);
    st(0, ra, rb);
  }
  __syncthreads();
  const int KT = KK / BK;
  for (int kt = 0; kt < KT; ++kt){
    int cur = kt & 1;
    float4 na[4]; int4 nb[2];
    if (kt + 1 < KT) ld(kt + 1, na, nb);
    bf16x8 af[4], bfr[4];
    #pragma unroll
    for (int i = 0; i < 4; ++i)
      af[i] = *reinterpret_cast<const bf16x8*>(&As[cur][wm*64 + i*16 + lr][lk]);
    #pragma unroll
    for (int i = 0; i < 4; ++i)
      bfr[i] = *reinterpret_cast<const bf16x8*>(&Bs[cur][wn*64 + i*16 + lr][lk]);
    #pragma unroll
    for (int i = 0; i < 4; ++i)
      #pragma unroll
      for (int j = 0; j < 4; ++j)
        acc[i][j] = __builtin_amdgcn_mfma_f32_16x16x32_bf16(af[i], bfr[j], acc[i][j], 0, 0, 0);
    if (kt + 1 < KT) st(cur ^ 1, na, nb);
    __syncthreads();
  }
  const int cm = mt * BM + wm * 64;
  const int cn = nt * BN + wn * 64;
  float bv[4];
  #pragma unroll
  for (int j = 0; j < 4; ++j) bv[j] = Bias[cn + j*16 + lr];
  #pragma unroll
  for (int i = 0; i < 4; ++i)
    #pragma unroll
    for (int j = 0; j < 4; ++j)
      #pragma unroll
      for (int r = 0; r < 4; ++r){
        size_t rr = (size_t)(cm + i*16 + (lane >> 4)*4 + r);
        C[rr * NN + (cn + j*16 + lr)] = acc[i][j][r] + bv[j];
      }
}

extern "C" void kernel_launch(void* const* d_in, const int* in_sizes, int n_in,
                              void* d_out, int out_size, void* d_ws, size_t ws_size,
                              hipStream_t stream){
  const float* x    = (const float*)d_in[0];   // fp32 [M][K] (fp16 ref -> float)
  const int*   w    = (const int*)d_in[1];     // [N][K/2] packed bytes
  const float* s    = (const float*)d_in[2];   // fp32 [N][NG]
  const float* bias = (const float*)d_in[3];   // fp32 [N]
  float* out = (float*)d_out;                  // fp32 [M][N]
  const int M = in_sizes[0] / KK;              // 8192
  const size_t needW = (size_t)NN * KK * 2;    // 90.2 MB for bf16 W
  const size_t needA = (size_t)M * KK * 2;     // 67.1 MB for bf16 x

  if (ws_size >= needW + needA && (M % BM2) == 0 && (M / BM2) == MT){
    unsigned short* wb = (unsigned short*)d_ws;
    unsigned short* xb = (unsigned short*)((char*)d_ws + needW);
    const int prep_blocks = DQ_BLOCKS + (M * (KK / 8)) / 256;   // 22016+16384
    k_prep<<<prep_blocks, 256, 0, stream>>>(w, s, x, wb, xb);
    const int grid16 = MT * NT_TILES;              // 1376
    k_gemm16<<<grid16, 1024, 0, stream>>>(xb, wb, bias, out);
  } else {
    unsigned short* wb = (unsigned short*)d_ws;
    k_dequant<<<DQ_BLOCKS, 256, 0, stream>>>(w, s, wb);
    const int grid = (M / BM) * (NN / BN);
    k_gemm_ws<<<grid, 256, 0, stream>>>(x, wb, bias, out);
  }
}

// Round 18
// 712.607 us; speedup vs baseline: 1.0776x; 1.0776x over previous
//
#include <hip/hip_runtime.h>

#define DEVINL __device__ __forceinline__

typedef __bf16 bf16x8 __attribute__((ext_vector_type(8)));
typedef float  f32x4  __attribute__((ext_vector_type(4)));

constexpr int KK = 4096;        // K
constexpr int NN = 11008;       // N
constexpr int NG = 32;          // K / group_size(128)

DEVINL unsigned short f2bf(float f){
  union { float f; unsigned u; } v; v.f = f;
  unsigned r = v.u + 0x7FFF + ((v.u >> 16) & 1);   // RNE; inputs finite here
  return (unsigned short)(r >> 16);
}
DEVINL unsigned pack2(float lo, float hi){
  return (unsigned)f2bf(lo) | ((unsigned)f2bf(hi) << 16);
}
DEVINL void gload16(const void* g, void* l){
  __builtin_amdgcn_global_load_lds(
      (const __attribute__((address_space(1))) void*)g,
      (__attribute__((address_space(3))) void*)l, 16, 0, 0);
}

// ---------------- pre-kernel 1: dequant W (int4-in-int32) -> bf16 [N][K] --
__global__ __launch_bounds__(256) void k_dequant(const int* __restrict__ W,
                                                 const float* __restrict__ S,
                                                 unsigned short* __restrict__ WB){
  int t = blockIdx.x * 256 + threadIdx.x;     // quad id; total NN*(KK/8)
  int row = t >> 9;                           // 512 quads per N-row
  int kp0 = (t & 511) << 2;
  int g   = kp0 >> 6;
  float s = S[row * NG + g];
  const int4 p = reinterpret_cast<const int4*>(W)[t];
  const int* pb = reinterpret_cast<const int*>(&p);
  unsigned q[4];
  #pragma unroll
  for (int i = 0; i < 4; ++i){
    int b = pb[i];
    float lo = ((float)(b & 15)        - 8.0f) * s;
    float hi = ((float)((b >> 4) & 15) - 8.0f) * s;
    q[i] = pack2(lo, hi);
  }
  reinterpret_cast<int4*>(WB)[t] = make_int4((int)q[0], (int)q[1], (int)q[2], (int)q[3]);
}

// ---------------- pre-kernel 2: convert x fp32 -> bf16 [M][K] -------------
__global__ __launch_bounds__(256) void k_cvtA(const float* __restrict__ X,
                                              unsigned short* __restrict__ XB){
  int t = blockIdx.x * 256 + threadIdx.x;
  const float4* src = reinterpret_cast<const float4*>(X) + (size_t)t * 2;
  float4 a = src[0], b = src[1];
  reinterpret_cast<int4*>(XB)[t] = make_int4(
      (int)pack2(a.x, a.y), (int)pack2(a.z, a.w),
      (int)pack2(b.x, b.y), (int)pack2(b.z, b.w));
}

// =================== R18 = R16 verbatim (session best: 729us total) =======
// 256x256 tile, 1024 thr = 16 waves (4m x 4n) x 64x64/wave, BK=64, dbuf.
// Each wave reads exactly ONE A-half and ONE B-half per K-tile -> 1 barrier
// + 1 own-wave vmcnt drain per tile; 16 waves drain the LDS read queue
// staggered so MFMA overlaps LDS service. acc 64 (AGPR) + frags 32 -> 64
// arch VGPR at 16 waves/CU (exactly the 128/wave budget).
// Session map (R5-R17, all measured):
//  - pipelined-read 4-phase (m201-class) needs ~260 regs/wave > 256 HW
//    budget -> acc spills (R13: 20GB scratch writes; R15: 2.6GB) -> infeasible
//  - tiles < 256^2 double panel refetch -> HBM-bound regime (R11: 930us)
//  - more barriers/tile (R6/R8) or more tiles (R14) -> lockstep overhead
//  - 16 waves/CU with 128x64/wave acc -> spill (R10: 7240us)
//  - banded raster halves FETCH (1.5->0.7GB) but costs 3-4% (R17) -> kernel
//    is NOT HBM-bound; binding constraint is LDS-read/MFMA serialization
//  - setprio on this lockstep structure: no gain (R16 == R9 within noise)
constexpr int BM2 = 256, BN2 = 256, BK2 = 64;
constexpr int HBY = 16384;      // half-tile bytes (128 rows x 64 K x bf16)
constexpr int BUFBY = 65536;    // one dbuf buffer (A0,A1,B0,B1)

#define WAIT0  asm volatile("s_waitcnt vmcnt(0)" ::: "memory")
#define BAR()  do { __builtin_amdgcn_s_barrier(); asm volatile("" ::: "memory"); } while (0)

__global__ __launch_bounds__(1024, 1) void k_gemm16(const unsigned short* __restrict__ A,
                                                    const unsigned short* __restrict__ B,
                                                    const float* __restrict__ Bias,
                                                    float* __restrict__ C){
  __shared__ char smem[131072];
  const int tid = threadIdx.x, lane = tid & 63, wid = tid >> 6;   // wid 0..15
  const int wm = wid >> 2, wn = wid & 3;       // 4 x 4 waves
  const int lr = lane & 15, hi = lane >> 4;
  // XCD-aware swizzle: grid = 1376, divisible by 8.
  const int cpx = gridDim.x >> 3;
  const int wg  = (blockIdx.x & 7) * cpx + (blockIdx.x >> 3);
  const int NTT = NN / BN2;                    // 43
  const int mt = wg / NTT, nt = wg % NTT;
  const char* Ab = (const char*)(A + (size_t)mt * BM2 * KK);
  const char* Bb = (const char*)(B + (size_t)nt * BN2 * KK);
  const int srow  = tid >> 3;                  // staging row (0..127)
  const int scolb = (tid & 7) * 16;            // staging col byte (0..112)

  // Stage one half-tile (sel: 0=A0,1=A1,2=B0,3=B1): 1 gload16 per thread.
  auto stage_half = [&](int buf, int sel, int kt){
    const char* base = ((sel >= 2) ? Bb : Ab) + (size_t)((sel & 1) * 128) * KK * 2;
    const char* src = base + (size_t)srow * (KK * 2) + kt * (BK2 * 2)
                    + (scolb ^ ((srow & 7) << 4));           // inverse-swizzled src
    char* dst = smem + buf * BUFBY + sel * HBY + tid * 16;   // linear dst
    gload16(src, dst);
  };
  // Swizzled LDS fragment read (16B).
  auto frag = [&](int buf, int sel, int row, int bcol) -> bf16x8 {
    return *reinterpret_cast<const bf16x8*>(
        smem + buf * BUFBY + sel * HBY + row * 128 + (bcol ^ ((row & 7) << 4)));
  };

  const int selA = wm >> 1;                    // this wave's A-half
  const int rA0  = (wm & 1) * 64;              // row base within half
  const int selB = 2 + (wn >> 1);              // this wave's B-half
  const int cB0  = (wn & 1) * 64;              // col base within half

  f32x4 acc[4][4] = {};

  // Prologue: stage all 4 halves of K-tile 0, drain, barrier.
  stage_half(0, 0, 0); stage_half(0, 1, 0);
  stage_half(0, 2, 0); stage_half(0, 3, 0);
  WAIT0;
  BAR();

  const int NT = KK / BK2;                     // 64 K-tiles
  for (int t = 0; t < NT; ++t){
    const int buf = t & 1;
    const bool pf = (t + 1 < NT);
    if (pf){                                   // issue next-tile stages first:
      stage_half(buf ^ 1, 0, t + 1);           // in flight across the whole
      stage_half(buf ^ 1, 1, t + 1);           // tile body -> HBM/L2 latency
      stage_half(buf ^ 1, 2, t + 1);           // covered before the WAIT0.
      stage_half(buf ^ 1, 3, t + 1);
    }
    #pragma unroll
    for (int ks = 0; ks < 2; ++ks){            // ks-split keeps frags at 32 VGPR
      bf16x8 af[4], bf[4];
      #pragma unroll
      for (int i = 0; i < 4; ++i)
        af[i] = frag(buf, selA, rA0 + i*16 + lr, ks*64 + hi*16);
      #pragma unroll
      for (int j = 0; j < 4; ++j)
        bf[j] = frag(buf, selB, cB0 + j*16 + lr, ks*64 + hi*16);
      #pragma unroll
      for (int i = 0; i < 4; ++i)
        #pragma unroll
        for (int j = 0; j < 4; ++j)
          acc[i][j] = __builtin_amdgcn_mfma_f32_16x16x32_bf16(af[i], bf[j], acc[i][j], 0, 0, 0);
    }
    if (pf) WAIT0;                             // own 4 stages landed (issued ~1 tile ago)
    BAR();                                     // all waves: staged data global, reads done
  }

  // Epilogue: bias + fp32 store.
  const int cmb = mt * BM2, cnb = nt * BN2;
  #pragma unroll
  for (int j = 0; j < 4; ++j){
    int col = cnb + wn * 64 + j * 16 + lr;
    float bv = Bias[col];
    #pragma unroll
    for (int i = 0; i < 4; ++i){
      int row0 = cmb + wm * 64 + i * 16 + hi * 4;
      #pragma unroll
      for (int r = 0; r < 4; ++r)
        C[(size_t)(row0 + r) * NN + col] = acc[i][j][r] + bv;
    }
  }
}

// ---------------- fallback (verified round 3): A fp32, reg-staged ---------
constexpr int BM = 128, BN = 128, BK = 32;
__global__ __launch_bounds__(256) void k_gemm_ws(const float* __restrict__ A,
                                                 const unsigned short* __restrict__ B,
                                                 const float* __restrict__ Bias,
                                                 float* __restrict__ C){
  __shared__ unsigned short As[2][BM][BK];
  __shared__ unsigned short Bs[2][BN][BK];
  const int tid = threadIdx.x;
  const int NT = NN / BN;
  const int mt = blockIdx.x / NT, nt = blockIdx.x % NT;
  const float*          Ab = A + (size_t)mt * BM * KK;
  const unsigned short* Bb = B + (size_t)nt * BN * KK;
  const int lane = tid & 63, wid = tid >> 6;
  const int wm = wid >> 1, wn = wid & 1;
  const int lr = lane & 15, lk = (lane >> 4) << 3;

  auto ld = [&](int kt, float4* ra, int4* rb){
    #pragma unroll
    for (int r = 0; r < 2; ++r){
      int c = r * 256 + tid, row = c >> 2, k0 = (c & 3) << 3;
      const float* src = Ab + (size_t)row * KK + kt * BK + k0;
      ra[2*r]   = *reinterpret_cast<const float4*>(src);
      ra[2*r+1] = *reinterpret_cast<const float4*>(src + 4);
      rb[r] = *reinterpret_cast<const int4*>(Bb + (size_t)row * KK + kt * BK + k0);
    }
  };
  auto st = [&](int buf, const float4* ra, const int4* rb){
    #pragma unroll
    for (int r = 0; r < 2; ++r){
      int c = r * 256 + tid, row = c >> 2, k0 = (c & 3) << 3;
      unsigned q[4];
      #pragma unroll
      for (int i = 0; i < 4; ++i)
        q[i] = pack2(ra[2*r + (i >> 1)][(i & 1) * 2], ra[2*r + (i >> 1)][(i & 1) * 2 + 1]);
      *reinterpret_cast<int4*>(&As[buf][row][k0]) =
          make_int4((int)q[0], (int)q[1], (int)q[2], (int)q[3]);
      *reinterpret_cast<int4*>(&Bs[buf][row][k0]) = rb[r];
    }
  };

  f32x4 acc[4][4] = {};
  {
    float4 ra[4]; int4 rb[2];
    ld(0, ra, rb);
    st(0, ra, rb);
  }
  __syncthreads();
  const int KT = KK / BK;
  for (int kt = 0; kt < KT; ++kt){
    int cur = kt & 1;
    float4 na[4]; int4 nb[2];
    if (kt + 1 < KT) ld(kt + 1, na, nb);
    bf16x8 af[4], bfr[4];
    #pragma unroll
    for (int i = 0; i < 4; ++i)
      af[i] = *reinterpret_cast<const bf16x8*>(&As[cur][wm*64 + i*16 + lr][lk]);
    #pragma unroll
    for (int i = 0; i < 4; ++i)
      bfr[i] = *reinterpret_cast<const bf16x8*>(&Bs[cur][wn*64 + i*16 + lr][lk]);
    #pragma unroll
    for (int i = 0; i < 4; ++i)
      #pragma unroll
      for (int j = 0; j < 4; ++j)
        acc[i][j] = __builtin_amdgcn_mfma_f32_16x16x32_bf16(af[i], bfr[j], acc[i][j], 0, 0, 0);
    if (kt + 1 < KT) st(cur ^ 1, na, nb);
    __syncthreads();
  }
  const int cm = mt * BM + wm * 64;
  const int cn = nt * BN + wn * 64;
  float bv[4];
  #pragma unroll
  for (int j = 0; j < 4; ++j) bv[j] = Bias[cn + j*16 + lr];
  #pragma unroll
  for (int i = 0; i < 4; ++i)
    #pragma unroll
    for (int j = 0; j < 4; ++j)
      #pragma unroll
      for (int r = 0; r < 4; ++r){
        size_t rr = (size_t)(cm + i*16 + (lane >> 4)*4 + r);
        C[rr * NN + (cn + j*16 + lr)] = acc[i][j][r] + bv[j];
      }
}

extern "C" void kernel_launch(void* const* d_in, const int* in_sizes, int n_in,
                              void* d_out, int out_size, void* d_ws, size_t ws_size,
                              hipStream_t stream){
  const float* x    = (const float*)d_in[0];   // fp32 [M][K] (fp16 ref -> float)
  const int*   w    = (const int*)d_in[1];     // [N][K/2] packed bytes
  const float* s    = (const float*)d_in[2];   // fp32 [N][NG]
  const float* bias = (const float*)d_in[3];   // fp32 [N]
  float* out = (float*)d_out;                  // fp32 [M][N]
  const int M = in_sizes[0] / KK;              // 8192
  const size_t needW = (size_t)NN * KK * 2;    // 90.2 MB for bf16 W
  const size_t needA = (size_t)M * KK * 2;     // 67.1 MB for bf16 x
  const int dq_blocks = (NN * (KK / 8)) / 256;

  if (ws_size >= needW + needA && (M % BM2) == 0){
    unsigned short* wb = (unsigned short*)d_ws;
    unsigned short* xb = (unsigned short*)((char*)d_ws + needW);
    k_dequant<<<dq_blocks, 256, 0, stream>>>(w, s, wb);
    k_cvtA<<<(M * (KK / 8)) / 256, 256, 0, stream>>>(x, xb);
    const int grid16 = (M / BM2) * (NN / BN2);     // 32*43 = 1376
    k_gemm16<<<grid16, 1024, 0, stream>>>(xb, wb, bias, out);
  } else {
    unsigned short* wb = (unsigned short*)d_ws;
    k_dequant<<<dq_blocks, 256, 0, stream>>>(w, s, wb);
    const int grid = (M / BM) * (NN / BN);
    k_gemm_ws<<<grid, 256, 0, stream>>>(x, wb, bias, out);
  }
}